// Round 1
// baseline (270.332 us; speedup 1.0000x reference)
//
#include <hip/hip_runtime.h>

// Problem constants
#define NB   8
#define NC   256
#define HW   56
#define NPX  (HW * HW)     // 3136
#define RED  64
#define NG   16
#define GC   16
#define KS   7
#define KK   49
#define PADK 3
#define W2T_STRIDE 56      // padded k-stride so rows are 16B-aligned

// ---------------------------------------------------------------------------
// K0: transpose w2 [784][64] -> w2t [64][16][56]  (w2t[r][g][k] = w2[g*49+k][r])
// ---------------------------------------------------------------------------
__global__ __launch_bounds__(256) void transpose_w2_kernel(
    const float* __restrict__ w2, float* __restrict__ w2t) {
    int idx = blockIdx.x * 256 + threadIdx.x;           // over 64*16*56
    if (idx >= RED * NG * W2T_STRIDE) return;
    int k = idx % W2T_STRIDE;
    int g = (idx / W2T_STRIDE) % NG;
    int r = idx / (W2T_STRIDE * NG);
    float v = 0.0f;
    if (k < KK) v = w2[(g * KK + k) * RED + r];
    w2t[idx] = v;
}

// ---------------------------------------------------------------------------
// K1: t = relu(bn1(conv1x1(x, w1)))   x:[B][256][3136] -> t:[B][64][3136]
// Block: 256 threads = 4 waves; wave oq handles outputs o = oq*16..oq*16+15
// for 64 consecutive pixels. w1 reads are wave-uniform -> scalar loads.
// ---------------------------------------------------------------------------
__global__ __launch_bounds__(256) void conv1_kernel(
    const float* __restrict__ x, const float* __restrict__ w1,
    const float* __restrict__ g1, const float* __restrict__ be1,
    const float* __restrict__ mu1, const float* __restrict__ var1,
    float* __restrict__ t) {
    int px = blockIdx.x * 64 + (threadIdx.x & 63);
    int b  = blockIdx.y;
    int oq = threadIdx.x >> 6;      // 0..3, wave-uniform

    const float* xb = x + (size_t)b * NC * NPX + px;
    float acc[16];
#pragma unroll
    for (int j = 0; j < 16; ++j) acc[j] = 0.0f;

#pragma unroll 4
    for (int c = 0; c < NC; ++c) {
        float xv = xb[(size_t)c * NPX];
#pragma unroll
        for (int j = 0; j < 16; ++j) {
            acc[j] = fmaf(xv, w1[(oq * 16 + j) * NC + c], acc[j]);
        }
    }

    float* tb = t + (size_t)b * RED * NPX + px;
#pragma unroll
    for (int j = 0; j < 16; ++j) {
        int o = oq * 16 + j;
        float inv = g1[o] * rsqrtf(var1[o] + 1e-5f);
        float v = acc[j] * inv + (be1[o] - mu1[o] * inv);
        tb[(size_t)o * NPX] = fmaxf(v, 0.0f);
    }
}

// ---------------------------------------------------------------------------
// K2: fused conv2(+bias) -> involution -> bn2 -> relu
// Grid: (49 tiles of 8x8, 16 groups, 8 batches). Block: 64 threads (1 wave),
// one thread per pixel of the 8x8 tile. Each thread:
//   phase A: wgt[49] in registers = b2 + sum_r t[r,px] * w2t[r][g][k]
//            (w2t read is wave-uniform -> SGPR loads; t load coalesced)
//   phase B: for each of the group's 16 channels: 49-tap weighted sum of x
//            (taps hit L1: block footprint 16c*14*14*4B = 12.5 KB), bn2+relu.
// ---------------------------------------------------------------------------
__global__ __launch_bounds__(64) void involution_kernel(
    const float* __restrict__ x, const float* __restrict__ t,
    const float* __restrict__ w2t, const float* __restrict__ b2,
    const float* __restrict__ g2, const float* __restrict__ be2,
    const float* __restrict__ mu2, const float* __restrict__ var2,
    float* __restrict__ out) {
    int tile = blockIdx.x;          // 0..48
    int g    = blockIdx.y;          // 0..15
    int b    = blockIdx.z;          // 0..7
    int h0 = (tile / 7) * 8;
    int w0 = (tile % 7) * 8;
    int lane = threadIdx.x;         // 0..63
    int py = lane >> 3, pw = lane & 7;
    int h = h0 + py, w = w0 + pw;
    int px = h * HW + w;

    // ---- phase A: wgt[49] in registers ----
    float wacc[KK];
#pragma unroll
    for (int k = 0; k < KK; ++k) wacc[k] = b2[g * KK + k];

    const float* tb = t + (size_t)b * RED * NPX + px;
#pragma unroll 2
    for (int r = 0; r < RED; ++r) {
        float tv = tb[(size_t)r * NPX];
        const float* wrow = w2t + (r * NG + g) * W2T_STRIDE;   // wave-uniform
#pragma unroll
        for (int k = 0; k < KK; ++k) {
            wacc[k] = fmaf(tv, wrow[k], wacc[k]);
        }
    }

    // ---- phase B: involution + bn2 + relu ----
    const float* xb = x + (size_t)b * NC * NPX;
    float* ob = out + (size_t)b * NC * NPX;
#pragma unroll 1
    for (int cl = 0; cl < GC; ++cl) {
        int c = g * GC + cl;
        const float* xc = xb + (size_t)c * NPX;
        float acc = 0.0f;
#pragma unroll
        for (int i = 0; i < KS; ++i) {
            int hh = h - PADK + i;
            bool hok = (hh >= 0) && (hh < HW);
#pragma unroll
            for (int j = 0; j < KS; ++j) {
                int ww = w - PADK + j;
                bool ok = hok && (ww >= 0) && (ww < HW);
                float xv = ok ? xc[hh * HW + ww] : 0.0f;
                acc = fmaf(wacc[i * KS + j], xv, acc);
            }
        }
        float inv = g2[c] * rsqrtf(var2[c] + 1e-5f);
        float v = acc * inv + (be2[c] - mu2[c] * inv);
        ob[(size_t)c * NPX + px] = fmaxf(v, 0.0f);
    }
}

// ---------------------------------------------------------------------------
extern "C" void kernel_launch(void* const* d_in, const int* in_sizes, int n_in,
                              void* d_out, int out_size, void* d_ws, size_t ws_size,
                              hipStream_t stream) {
    const float* x    = (const float*)d_in[0];
    const float* w1   = (const float*)d_in[1];
    const float* g1   = (const float*)d_in[2];
    const float* be1  = (const float*)d_in[3];
    const float* mu1  = (const float*)d_in[4];
    const float* var1 = (const float*)d_in[5];
    const float* w2   = (const float*)d_in[6];
    const float* b2   = (const float*)d_in[7];
    const float* g2   = (const float*)d_in[8];
    const float* be2  = (const float*)d_in[9];
    const float* mu2  = (const float*)d_in[10];
    const float* var2 = (const float*)d_in[11];
    float* outp = (float*)d_out;

    // ws layout: t (B*64*3136 fp32 = 6.42 MB) then w2t (64*16*56 fp32 = 229 KB)
    float* t   = (float*)d_ws;
    float* w2t = (float*)((char*)d_ws + (size_t)NB * RED * NPX * sizeof(float));

    // K0: transpose w2
    {
        int n = RED * NG * W2T_STRIDE;
        transpose_w2_kernel<<<(n + 255) / 256, 256, 0, stream>>>(w2, w2t);
    }
    // K1: conv1 + bn1 + relu
    conv1_kernel<<<dim3(NPX / 64, NB), 256, 0, stream>>>(x, w1, g1, be1, mu1, var1, t);
    // K2: fused conv2 + involution + bn2 + relu
    involution_kernel<<<dim3(49, NG, NB), 64, 0, stream>>>(x, t, w2t, b2, g2, be2, mu2, var2, outp);
}

// Round 2
// 244.978 us; speedup vs baseline: 1.1035x; 1.1035x over previous
//
#include <hip/hip_runtime.h>

// Problem constants
#define NB   8
#define NC   256
#define HW   56
#define NPX  (HW * HW)     // 3136
#define RED  64
#define NG   16
#define GC   16
#define KS   7
#define KK   49
#define PADK 3

// ---------------------------------------------------------------------------
// K1: t = relu(bn1(conv1x1(x, w1)))   x:[B][256][3136] -> t:[B][64][3136]
// Grid (49 px-tiles, 8 r-splits, 8 batches), 64 threads (1 wave).
// Lane = pixel (coalesced). Wave computes 8 outputs. Inner loop: batch-load
// 16 independent x values (16 loads in flight -> hides HBM latency), then
// 8x16 FMA block with wave-uniform w1 (SGPR operands).
// ---------------------------------------------------------------------------
__global__ __launch_bounds__(64) void conv1_kernel(
    const float* __restrict__ x, const float* __restrict__ w1,
    const float* __restrict__ g1, const float* __restrict__ be1,
    const float* __restrict__ mu1, const float* __restrict__ var1,
    float* __restrict__ t) {
    int px = blockIdx.x * 64 + threadIdx.x;
    int rq = blockIdx.y;            // outputs rq*8 .. rq*8+7
    int b  = blockIdx.z;

    const float* xb = x + (size_t)b * NC * NPX + px;
    float acc[8];
#pragma unroll
    for (int j = 0; j < 8; ++j) acc[j] = 0.0f;

#pragma unroll 1
    for (int c0 = 0; c0 < NC; c0 += 16) {
        float xv[16];
#pragma unroll
        for (int i = 0; i < 16; ++i) xv[i] = xb[(size_t)(c0 + i) * NPX];
#pragma unroll
        for (int j = 0; j < 8; ++j) {
            const float* wrow = w1 + (rq * 8 + j) * NC + c0;   // wave-uniform
#pragma unroll
            for (int i = 0; i < 16; ++i)
                acc[j] = fmaf(xv[i], wrow[i], acc[j]);
        }
    }

    float* tb = t + (size_t)b * RED * NPX + px;
#pragma unroll
    for (int j = 0; j < 8; ++j) {
        int o = rq * 8 + j;
        float inv = g1[o] * rsqrtf(var1[o] + 1e-5f);
        float v = acc[j] * inv + (be1[o] - mu1[o] * inv);
        tb[(size_t)o * NPX] = fmaxf(v, 0.0f);
    }
}

// ---------------------------------------------------------------------------
// K2: fused conv2(+bias) -> involution -> bn2 -> relu
// Grid (49 linear 64-px tiles, 16 groups, 8 batches), 64 threads (1 wave).
// Lane = pixel (linear tile -> fully coalesced t loads / out stores; tap
// footprint = ~9 full-width rows x 16 ch = 32 KB, L1-resident with full
// cache-line utilization).
// Phase A: wgt[49] in regs. Batch-load 16 t values, then 49x16 FMA with
//          wave-uniform w2 (native [g][49][64] layout -> s_load_dwordx16).
// Phase B: per channel load all 49 taps into regs (deep MLP, L1 hits),
//          2-chain dot product, bn2+relu, coalesced store.
// ---------------------------------------------------------------------------
__global__ __launch_bounds__(64) void involution_kernel(
    const float* __restrict__ x, const float* __restrict__ t,
    const float* __restrict__ w2, const float* __restrict__ b2,
    const float* __restrict__ g2, const float* __restrict__ be2,
    const float* __restrict__ mu2, const float* __restrict__ var2,
    float* __restrict__ out) {
    int px = blockIdx.x * 64 + threadIdx.x;   // linear pixel
    int g  = blockIdx.y;
    int b  = blockIdx.z;
    int h = px / HW, w = px % HW;

    // ---- phase A: wgt[49] in registers ----
    float wacc[KK];
#pragma unroll
    for (int k = 0; k < KK; ++k) wacc[k] = b2[g * KK + k];

    const float* tb = t + (size_t)b * RED * NPX + px;
    const float* wg = w2 + (size_t)g * KK * RED;   // [49][64], wave-uniform

#pragma unroll 1
    for (int r0 = 0; r0 < RED; r0 += 16) {
        float tv[16];
#pragma unroll
        for (int i = 0; i < 16; ++i) tv[i] = tb[(size_t)(r0 + i) * NPX];
#pragma unroll
        for (int k = 0; k < KK; ++k) {
            const float* wk = wg + k * RED + r0;   // 16 consecutive -> s_load
#pragma unroll
            for (int i = 0; i < 16; ++i)
                wacc[k] = fmaf(tv[i], wk[i], wacc[k]);
        }
    }

    // ---- phase B: involution + bn2 + relu ----
    const float* xb = x + (size_t)b * NC * NPX;
    float* ob = out + (size_t)b * NC * NPX + px;
#pragma unroll 1
    for (int cl = 0; cl < GC; ++cl) {
        int c = g * GC + cl;
        const float* xc = xb + (size_t)c * NPX;
        // load all 49 taps (independent -> deep memory-level parallelism)
        float xr[KK];
#pragma unroll
        for (int i = 0; i < KS; ++i) {
            int hh = h - PADK + i;
            bool hok = (hh >= 0) && (hh < HW);
            const float* xrow = xc + hh * HW + (w - PADK);
#pragma unroll
            for (int j = 0; j < KS; ++j) {
                int ww = w - PADK + j;
                bool ok = hok && (ww >= 0) && (ww < HW);
                xr[i * KS + j] = ok ? xrow[j] : 0.0f;
            }
        }
        // two accumulator chains to halve dependent-FMA latency
        float a0 = 0.0f, a1 = 0.0f;
#pragma unroll
        for (int k = 0; k < 48; k += 2) {
            a0 = fmaf(wacc[k], xr[k], a0);
            a1 = fmaf(wacc[k + 1], xr[k + 1], a1);
        }
        a0 = fmaf(wacc[48], xr[48], a0);
        float acc = a0 + a1;

        float inv = g2[c] * rsqrtf(var2[c] + 1e-5f);
        float v = acc * inv + (be2[c] - mu2[c] * inv);
        ob[(size_t)c * NPX] = fmaxf(v, 0.0f);
    }
}

// ---------------------------------------------------------------------------
extern "C" void kernel_launch(void* const* d_in, const int* in_sizes, int n_in,
                              void* d_out, int out_size, void* d_ws, size_t ws_size,
                              hipStream_t stream) {
    const float* x    = (const float*)d_in[0];
    const float* w1   = (const float*)d_in[1];
    const float* g1   = (const float*)d_in[2];
    const float* be1  = (const float*)d_in[3];
    const float* mu1  = (const float*)d_in[4];
    const float* var1 = (const float*)d_in[5];
    const float* w2   = (const float*)d_in[6];
    const float* b2   = (const float*)d_in[7];
    const float* g2   = (const float*)d_in[8];
    const float* be2  = (const float*)d_in[9];
    const float* mu2  = (const float*)d_in[10];
    const float* var2 = (const float*)d_in[11];
    float* outp = (float*)d_out;

    float* t = (float*)d_ws;   // B*64*3136 fp32 = 6.42 MB

    // K1: conv1 + bn1 + relu
    conv1_kernel<<<dim3(NPX / 64, 8, NB), 64, 0, stream>>>(
        x, w1, g1, be1, mu1, var1, t);
    // K2: fused conv2 + involution + bn2 + relu  (w2 used in native layout)
    involution_kernel<<<dim3(NPX / 64, NG, NB), 64, 0, stream>>>(
        x, t, w2, b2, g2, be2, mu2, var2, outp);
}